// Round 1
// baseline (2773.372 us; speedup 1.0000x reference)
//
#include <hip/hip_runtime.h>

#define FPS_N 32768
#define FPS_T 1024
#define FPS_K 32      // points per thread
#define NQ 256
#define DD 256
#define NT 64         // n-tile for MLP kernel
#define B_BATCH 64

// ---------------------------------------------------------------------------
// Kernel 1: furthest point sampling, one block per batch.
// Coordinates in registers (32/thread), running min-dist in LDS (128KB).
// Arithmetic matches numpy bitwise: sub, mul, add (no FMA contraction), fminf.
// Tie-break: first occurrence (smallest index) like jnp.argmax.
// ---------------------------------------------------------------------------
__global__ __launch_bounds__(FPS_T) void fps_kernel(const float* __restrict__ xyz,
                                                    float* __restrict__ qout) {
  const int b = blockIdx.x;
  const int t = threadIdx.x;
  const float* base = xyz + (size_t)b * (FPS_N * 3);
  float* qb = qout + (size_t)b * (NQ * 3);

  __shared__ float sdist[FPS_N];          // 128 KB
  __shared__ float scen[3];
  __shared__ float rval[FPS_T / 64];
  __shared__ int   ridx[FPS_T / 64];
  __shared__ int   sfar;

  float px[FPS_K], py[FPS_K], pz[FPS_K];
#pragma unroll
  for (int k = 0; k < FPS_K; ++k) {
    const int p = k * FPS_T + t;
    px[k] = base[3 * p + 0];
    py[k] = base[3 * p + 1];
    pz[k] = base[3 * p + 2];
    sdist[p] = 1e10f;
  }
  if (t == 0) {
    scen[0] = px[0]; scen[1] = py[0]; scen[2] = pz[0];
    qb[0] = px[0]; qb[1] = py[0]; qb[2] = pz[0];   // inds[0] == 0 always
  }
  __syncthreads();
  float cx = scen[0], cy = scen[1], cz = scen[2];

  for (int j = 1; j < NQ; ++j) {
    float best = -1.0f;
    int bestk = 0;
#pragma unroll
    for (int k = 0; k < FPS_K; ++k) {
      const int p = k * FPS_T + t;
      const float dx = __fsub_rn(px[k], cx);
      const float dy = __fsub_rn(py[k], cy);
      const float dz = __fsub_rn(pz[k], cz);
      // numpy order: (dx^2 + dy^2) + dz^2, no fma
      const float d = __fadd_rn(__fadd_rn(__fmul_rn(dx, dx), __fmul_rn(dy, dy)),
                                __fmul_rn(dz, dz));
      const float nd = fminf(sdist[p], d);
      sdist[p] = nd;
      if (nd > best) { best = nd; bestk = k; }   // strict > keeps smallest k
    }
    float bv = best;
    int bi = bestk * FPS_T + t;
    // wave (64-lane) argmax reduce with first-index tie-break
#pragma unroll
    for (int off = 32; off; off >>= 1) {
      const float ov = __shfl_xor(bv, off);
      const int oi = __shfl_xor(bi, off);
      if (ov > bv || (ov == bv && oi < bi)) { bv = ov; bi = oi; }
    }
    if ((t & 63) == 0) { rval[t >> 6] = bv; ridx[t >> 6] = bi; }
    __syncthreads();
    if (t == 0) {
      float fv = rval[0]; int fi = ridx[0];
      for (int w = 1; w < FPS_T / 64; ++w) {
        const float ov = rval[w]; const int oi = ridx[w];
        if (ov > fv || (ov == fv && oi < fi)) { fv = ov; fi = oi; }
      }
      sfar = fi;
    }
    __syncthreads();
    const int far = sfar;
    const int ft = far & (FPS_T - 1);
    const int fk = far >> 10;
    if (t == ft) {
      float sx = 0.f, sy = 0.f, sz = 0.f;
#pragma unroll
      for (int k = 0; k < FPS_K; ++k) {
        if (k == fk) { sx = px[k]; sy = py[k]; sz = pz[k]; }
      }
      scen[0] = sx; scen[1] = sy; scen[2] = sz;
      qb[3 * j + 0] = sx; qb[3 * j + 1] = sy; qb[3 * j + 2] = sz;
    }
    __syncthreads();
    cx = scen[0]; cy = scen[1]; cz = scen[2];
  }
}

// ---------------------------------------------------------------------------
// Kernel 2: fourier positional embedding + 2-layer MLP, fused.
// One block per (batch, 64-query tile). pos and h staged in LDS, W tiles
// staged transposed in LDS, 4x4 micro-tile f32 FMA GEMM.
// ---------------------------------------------------------------------------
__global__ __launch_bounds__(256) void embed_mlp_kernel(
    const float* __restrict__ qxyz, const float* __restrict__ pcmin,
    const float* __restrict__ pcmax, const float* __restrict__ G,
    const float* __restrict__ W1, const float* __restrict__ b1,
    const float* __restrict__ W2, const float* __restrict__ b2,
    float* __restrict__ out) {
  const int b = blockIdx.x >> 2;
  const int n0 = (blockIdx.x & 3) * NT;
  const int tid = threadIdx.x;
  const int ty = tid >> 4, tx = tid & 15;

  __shared__ __align__(16) float P[DD][NT + 4];   // pos, 69632 B
  __shared__ __align__(16) float H[DD][NT + 4];   // hidden, 69632 B
  __shared__ __align__(16) float Wl[64][NT + 4];  // W tile (transposed), 17408 B
  __shared__ float snorm[NT][3];

  // --- normalized query coords ---
  if (tid < NT) {
    const int n = n0 + tid;
    const float qx = qxyz[(size_t)b * (NQ * 3) + 3 * n + 0];
    const float qy = qxyz[(size_t)b * (NQ * 3) + 3 * n + 1];
    const float qz = qxyz[(size_t)b * (NQ * 3) + 3 * n + 2];
    snorm[tid][0] = (qx - pcmin[3 * b + 0]) / (pcmax[3 * b + 0] - pcmin[3 * b + 0]);
    snorm[tid][1] = (qy - pcmin[3 * b + 1]) / (pcmax[3 * b + 1] - pcmin[3 * b + 1]);
    snorm[tid][2] = (qz - pcmin[3 * b + 2]) / (pcmax[3 * b + 2] - pcmin[3 * b + 2]);
  }
  __syncthreads();

  // --- pos = [sin(proj); cos(proj)], P[c][n] ---
  {
    const int nn = tid & 63;
    const int fg = tid >> 6;   // 0..3
    const float nx = snorm[nn][0], ny = snorm[nn][1], nz = snorm[nn][2];
#pragma unroll 4
    for (int ff = 0; ff < 32; ++ff) {
      const int f = fg * 32 + ff;
      const float s = nx * G[f] + ny * G[128 + f] + nz * G[256 + f];
      const float proj = 6.28318530717958647692f * s;
      P[f][nn] = sinf(proj);
      P[f + 128][nn] = cosf(proj);
    }
  }

  // --- two GEMM layers: H = relu(W1*P + b1); OUT = relu(W2*H + b2) ---
  for (int layer = 0; layer < 2; ++layer) {
    const float* W = layer ? W2 : W1;
    const float* bias = layer ? b2 : b1;
    const float (*src)[NT + 4] = layer ? H : P;

    for (int dt = 0; dt < 4; ++dt) {
      float acc[4][4] = {};
      for (int kt = 0; kt < 4; ++kt) {
        __syncthreads();
        {  // stage W tile transposed: Wl[c][d] = W[dt*64+d][kt*64+c]
          const int r = tid >> 2;          // 0..63 : d within tile
          const int cb = (tid & 3) * 16;   // c base within tile
          const float* wrow = W + (size_t)(dt * 64 + r) * DD + kt * 64 + cb;
#pragma unroll
          for (int i = 0; i < 4; ++i) {
            const float4 v = *(const float4*)(wrow + 4 * i);
            Wl[cb + 4 * i + 0][r] = v.x;
            Wl[cb + 4 * i + 1][r] = v.y;
            Wl[cb + 4 * i + 2][r] = v.z;
            Wl[cb + 4 * i + 3][r] = v.w;
          }
        }
        __syncthreads();
#pragma unroll 8
        for (int cc = 0; cc < 64; ++cc) {
          const float4 a = *(const float4*)&Wl[cc][ty * 4];
          const float4 p4 = *(const float4*)&src[kt * 64 + cc][tx * 4];
          acc[0][0] = fmaf(a.x, p4.x, acc[0][0]);
          acc[0][1] = fmaf(a.x, p4.y, acc[0][1]);
          acc[0][2] = fmaf(a.x, p4.z, acc[0][2]);
          acc[0][3] = fmaf(a.x, p4.w, acc[0][3]);
          acc[1][0] = fmaf(a.y, p4.x, acc[1][0]);
          acc[1][1] = fmaf(a.y, p4.y, acc[1][1]);
          acc[1][2] = fmaf(a.y, p4.z, acc[1][2]);
          acc[1][3] = fmaf(a.y, p4.w, acc[1][3]);
          acc[2][0] = fmaf(a.z, p4.x, acc[2][0]);
          acc[2][1] = fmaf(a.z, p4.y, acc[2][1]);
          acc[2][2] = fmaf(a.z, p4.z, acc[2][2]);
          acc[2][3] = fmaf(a.z, p4.w, acc[2][3]);
          acc[3][0] = fmaf(a.w, p4.x, acc[3][0]);
          acc[3][1] = fmaf(a.w, p4.y, acc[3][1]);
          acc[3][2] = fmaf(a.w, p4.z, acc[3][2]);
          acc[3][3] = fmaf(a.w, p4.w, acc[3][3]);
        }
      }
      // epilogue: bias + relu
      if (layer == 0) {
#pragma unroll
        for (int i = 0; i < 4; ++i) {
          const float bv = bias[dt * 64 + ty * 4 + i];
          float4 h;
          h.x = fmaxf(acc[i][0] + bv, 0.f);
          h.y = fmaxf(acc[i][1] + bv, 0.f);
          h.z = fmaxf(acc[i][2] + bv, 0.f);
          h.w = fmaxf(acc[i][3] + bv, 0.f);
          *(float4*)&H[dt * 64 + ty * 4 + i][tx * 4] = h;
        }
      } else {
        float* ob = out + (size_t)b * (DD * NQ);
#pragma unroll
        for (int i = 0; i < 4; ++i) {
          const float bv = bias[dt * 64 + ty * 4 + i];
          float4 h;
          h.x = fmaxf(acc[i][0] + bv, 0.f);
          h.y = fmaxf(acc[i][1] + bv, 0.f);
          h.z = fmaxf(acc[i][2] + bv, 0.f);
          h.w = fmaxf(acc[i][3] + bv, 0.f);
          *(float4*)(ob + (size_t)(dt * 64 + ty * 4 + i) * NQ + n0 + tx * 4) = h;
        }
      }
    }
  }
}

extern "C" void kernel_launch(void* const* d_in, const int* in_sizes, int n_in,
                              void* d_out, int out_size, void* d_ws, size_t ws_size,
                              hipStream_t stream) {
  (void)in_sizes; (void)n_in; (void)d_ws; (void)ws_size; (void)out_size;
  const float* xyz   = (const float*)d_in[0];
  const float* pcmin = (const float*)d_in[1];
  const float* pcmax = (const float*)d_in[2];
  const float* G     = (const float*)d_in[3];
  const float* W1    = (const float*)d_in[4];
  const float* b1    = (const float*)d_in[5];
  const float* W2    = (const float*)d_in[6];
  const float* b2    = (const float*)d_in[7];

  float* qxyz  = (float*)d_out;                       // [64][256][3]
  float* embed = qxyz + (size_t)B_BATCH * NQ * 3;     // [64][256][256]

  hipLaunchKernelGGL(fps_kernel, dim3(B_BATCH), dim3(FPS_T), 0, stream, xyz, qxyz);
  hipLaunchKernelGGL(embed_mlp_kernel, dim3(B_BATCH * 4), dim3(256), 0, stream,
                     qxyz, pcmin, pcmax, G, W1, b1, W2, b2, embed);
}

// Round 2
// 1933.551 us; speedup vs baseline: 1.4343x; 1.4343x over previous
//
#include <hip/hip_runtime.h>

#define FPS_N 32768
#define FPS_T 1024
#define FPS_K 32      // points per thread
#define CHUNK 8       // pipeline chunk (double-buffered coord reload)
#define NQ 256
#define DD 256
#define NT 64         // n-tile for MLP kernel
#define B_BATCH 64

// ---------------------------------------------------------------------------
// Kernel 1: furthest point sampling, one block per batch.
// Running min-dist lives in REGISTERS (32/thread). Coordinates are re-streamed
// from L2 each iteration via a double-buffered 8-point chunk pipeline (the
// per-XCD working set, 8 blocks x 384KB = 3MB, is L2-resident).
// Arithmetic matches numpy bitwise: sub, mul, add (no FMA contraction), fminf.
// Tie-break: first occurrence (smallest index) like jnp.argmax.
// One barrier per iteration (parity double-buffered reduction slots).
// ---------------------------------------------------------------------------
__global__ __launch_bounds__(FPS_T) void fps_kernel(const float* __restrict__ xyz,
                                                    float* __restrict__ qout) {
  const int b = blockIdx.x;
  const int t = threadIdx.x;
  const float* __restrict__ base = xyz + (size_t)b * (FPS_N * 3);
  float* qb = qout + (size_t)b * (NQ * 3);

  __shared__ float2 red[2][FPS_T / 64];   // (val, idx-bits), parity-buffered

  float dist[FPS_K];
#pragma unroll
  for (int k = 0; k < FPS_K; ++k) dist[k] = 1e10f;

  if (t == 0) { qb[0] = base[0]; qb[1] = base[1]; qb[2] = base[2]; }  // inds[0]==0
  float cx = base[0], cy = base[1], cz = base[2];

  for (int j = 1; j < NQ; ++j) {
    float best = -1.0f;
    int bi = 0;

    float lx[2][CHUNK], ly[2][CHUNK], lz[2][CHUNK];
    // prefetch chunk 0
#pragma unroll
    for (int i = 0; i < CHUNK; ++i) {
      const int p = i * FPS_T + t;
      lx[0][i] = base[3 * p + 0];
      ly[0][i] = base[3 * p + 1];
      lz[0][i] = base[3 * p + 2];
    }
#pragma unroll
    for (int c = 0; c < FPS_K / CHUNK; ++c) {
      const int cur = c & 1;
      if (c + 1 < FPS_K / CHUNK) {   // prefetch next chunk into other buffer
        const int nxt = cur ^ 1;
#pragma unroll
        for (int i = 0; i < CHUNK; ++i) {
          const int p = ((c + 1) * CHUNK + i) * FPS_T + t;
          lx[nxt][i] = base[3 * p + 0];
          ly[nxt][i] = base[3 * p + 1];
          lz[nxt][i] = base[3 * p + 2];
        }
      }
#pragma unroll
      for (int i = 0; i < CHUNK; ++i) {
        const int k = c * CHUNK + i;
        const float dx = __fsub_rn(lx[cur][i], cx);
        const float dy = __fsub_rn(ly[cur][i], cy);
        const float dz = __fsub_rn(lz[cur][i], cz);
        // numpy order: (dx^2 + dy^2) + dz^2, no fma
        const float d = __fadd_rn(__fadd_rn(__fmul_rn(dx, dx), __fmul_rn(dy, dy)),
                                  __fmul_rn(dz, dz));
        const float nd = fminf(dist[k], d);
        dist[k] = nd;
        if (nd > best) { best = nd; bi = k * FPS_T + t; }  // strict >: first occurrence
      }
    }

    // wave (64-lane) argmax reduce with first-index tie-break
#pragma unroll
    for (int off = 32; off; off >>= 1) {
      const float ov = __shfl_xor(best, off);
      const int oi = __shfl_xor(bi, off);
      if (ov > best || (ov == best && oi < bi)) { best = ov; bi = oi; }
    }
    if ((t & 63) == 0) {
      red[j & 1][t >> 6] = make_float2(best, __int_as_float(bi));
    }
    __syncthreads();
    // every thread reduces the 16 wave results redundantly (broadcast reads)
    float fv;
    int fi;
    {
      const float2 r0 = red[j & 1][0];
      fv = r0.x;
      fi = __float_as_int(r0.y);
#pragma unroll
      for (int w = 1; w < FPS_T / 64; ++w) {
        const float2 r = red[j & 1][w];
        const float ov = r.x;
        const int oi = __float_as_int(r.y);
        if (ov > fv || (ov == fv && oi < fi)) { fv = ov; fi = oi; }
      }
    }
    // fetch new centroid from global (same-address broadcast, L2-hot)
    const float* cp = base + 3 * (size_t)fi;
    cx = cp[0]; cy = cp[1]; cz = cp[2];
    if (t == 0) { qb[3 * j + 0] = cx; qb[3 * j + 1] = cy; qb[3 * j + 2] = cz; }
  }
}

// ---------------------------------------------------------------------------
// Kernel 2: fourier positional embedding + 2-layer MLP, fused. (unchanged)
// ---------------------------------------------------------------------------
__global__ __launch_bounds__(256) void embed_mlp_kernel(
    const float* __restrict__ qxyz, const float* __restrict__ pcmin,
    const float* __restrict__ pcmax, const float* __restrict__ G,
    const float* __restrict__ W1, const float* __restrict__ b1,
    const float* __restrict__ W2, const float* __restrict__ b2,
    float* __restrict__ out) {
  const int b = blockIdx.x >> 2;
  const int n0 = (blockIdx.x & 3) * NT;
  const int tid = threadIdx.x;
  const int ty = tid >> 4, tx = tid & 15;

  __shared__ __align__(16) float P[DD][NT + 4];   // pos
  __shared__ __align__(16) float H[DD][NT + 4];   // hidden
  __shared__ __align__(16) float Wl[64][NT + 4];  // W tile (transposed)
  __shared__ float snorm[NT][3];

  if (tid < NT) {
    const int n = n0 + tid;
    const float qx = qxyz[(size_t)b * (NQ * 3) + 3 * n + 0];
    const float qy = qxyz[(size_t)b * (NQ * 3) + 3 * n + 1];
    const float qz = qxyz[(size_t)b * (NQ * 3) + 3 * n + 2];
    snorm[tid][0] = (qx - pcmin[3 * b + 0]) / (pcmax[3 * b + 0] - pcmin[3 * b + 0]);
    snorm[tid][1] = (qy - pcmin[3 * b + 1]) / (pcmax[3 * b + 1] - pcmin[3 * b + 1]);
    snorm[tid][2] = (qz - pcmin[3 * b + 2]) / (pcmax[3 * b + 2] - pcmin[3 * b + 2]);
  }
  __syncthreads();

  {
    const int nn = tid & 63;
    const int fg = tid >> 6;   // 0..3
    const float nx = snorm[nn][0], ny = snorm[nn][1], nz = snorm[nn][2];
#pragma unroll 4
    for (int ff = 0; ff < 32; ++ff) {
      const int f = fg * 32 + ff;
      const float s = nx * G[f] + ny * G[128 + f] + nz * G[256 + f];
      const float proj = 6.28318530717958647692f * s;
      P[f][nn] = sinf(proj);
      P[f + 128][nn] = cosf(proj);
    }
  }

  for (int layer = 0; layer < 2; ++layer) {
    const float* W = layer ? W2 : W1;
    const float* bias = layer ? b2 : b1;
    const float (*src)[NT + 4] = layer ? H : P;

    for (int dt = 0; dt < 4; ++dt) {
      float acc[4][4] = {};
      for (int kt = 0; kt < 4; ++kt) {
        __syncthreads();
        {  // stage W tile transposed: Wl[c][d] = W[dt*64+d][kt*64+c]
          const int r = tid >> 2;
          const int cb = (tid & 3) * 16;
          const float* wrow = W + (size_t)(dt * 64 + r) * DD + kt * 64 + cb;
#pragma unroll
          for (int i = 0; i < 4; ++i) {
            const float4 v = *(const float4*)(wrow + 4 * i);
            Wl[cb + 4 * i + 0][r] = v.x;
            Wl[cb + 4 * i + 1][r] = v.y;
            Wl[cb + 4 * i + 2][r] = v.z;
            Wl[cb + 4 * i + 3][r] = v.w;
          }
        }
        __syncthreads();
#pragma unroll 8
        for (int cc = 0; cc < 64; ++cc) {
          const float4 a = *(const float4*)&Wl[cc][ty * 4];
          const float4 p4 = *(const float4*)&src[kt * 64 + cc][tx * 4];
          acc[0][0] = fmaf(a.x, p4.x, acc[0][0]);
          acc[0][1] = fmaf(a.x, p4.y, acc[0][1]);
          acc[0][2] = fmaf(a.x, p4.z, acc[0][2]);
          acc[0][3] = fmaf(a.x, p4.w, acc[0][3]);
          acc[1][0] = fmaf(a.y, p4.x, acc[1][0]);
          acc[1][1] = fmaf(a.y, p4.y, acc[1][1]);
          acc[1][2] = fmaf(a.y, p4.z, acc[1][2]);
          acc[1][3] = fmaf(a.y, p4.w, acc[1][3]);
          acc[2][0] = fmaf(a.z, p4.x, acc[2][0]);
          acc[2][1] = fmaf(a.z, p4.y, acc[2][1]);
          acc[2][2] = fmaf(a.z, p4.z, acc[2][2]);
          acc[2][3] = fmaf(a.z, p4.w, acc[2][3]);
          acc[3][0] = fmaf(a.w, p4.x, acc[3][0]);
          acc[3][1] = fmaf(a.w, p4.y, acc[3][1]);
          acc[3][2] = fmaf(a.w, p4.z, acc[3][2]);
          acc[3][3] = fmaf(a.w, p4.w, acc[3][3]);
        }
      }
      if (layer == 0) {
#pragma unroll
        for (int i = 0; i < 4; ++i) {
          const float bv = bias[dt * 64 + ty * 4 + i];
          float4 h;
          h.x = fmaxf(acc[i][0] + bv, 0.f);
          h.y = fmaxf(acc[i][1] + bv, 0.f);
          h.z = fmaxf(acc[i][2] + bv, 0.f);
          h.w = fmaxf(acc[i][3] + bv, 0.f);
          *(float4*)&H[dt * 64 + ty * 4 + i][tx * 4] = h;
        }
      } else {
        float* ob = out + (size_t)b * (DD * NQ);
#pragma unroll
        for (int i = 0; i < 4; ++i) {
          const float bv = bias[dt * 64 + ty * 4 + i];
          float4 h;
          h.x = fmaxf(acc[i][0] + bv, 0.f);
          h.y = fmaxf(acc[i][1] + bv, 0.f);
          h.z = fmaxf(acc[i][2] + bv, 0.f);
          h.w = fmaxf(acc[i][3] + bv, 0.f);
          *(float4*)(ob + (size_t)(dt * 64 + ty * 4 + i) * NQ + n0 + tx * 4) = h;
        }
      }
    }
  }
}

extern "C" void kernel_launch(void* const* d_in, const int* in_sizes, int n_in,
                              void* d_out, int out_size, void* d_ws, size_t ws_size,
                              hipStream_t stream) {
  (void)in_sizes; (void)n_in; (void)d_ws; (void)ws_size; (void)out_size;
  const float* xyz   = (const float*)d_in[0];
  const float* pcmin = (const float*)d_in[1];
  const float* pcmax = (const float*)d_in[2];
  const float* G     = (const float*)d_in[3];
  const float* W1    = (const float*)d_in[4];
  const float* b1    = (const float*)d_in[5];
  const float* W2    = (const float*)d_in[6];
  const float* b2    = (const float*)d_in[7];

  float* qxyz  = (float*)d_out;                       // [64][256][3]
  float* embed = qxyz + (size_t)B_BATCH * NQ * 3;     // [64][256][256]

  hipLaunchKernelGGL(fps_kernel, dim3(B_BATCH), dim3(FPS_T), 0, stream, xyz, qxyz);
  hipLaunchKernelGGL(embed_mlp_kernel, dim3(B_BATCH * 4), dim3(256), 0, stream,
                     qxyz, pcmin, pcmax, G, W1, b1, W2, b2, embed);
}